// Round 8
// baseline (1045.182 us; speedup 1.0000x reference)
//
#include <hip/hip_runtime.h>
#include <cstdio>

#define B_   256
#define H_   512
#define G4_  2048
#define T_   326
#define OUT_ 9

typedef __attribute__((ext_vector_type(8))) short s16x8;
typedef __attribute__((ext_vector_type(4))) float f32x4;
typedef unsigned long long ull;

__device__ inline unsigned short to_bf16(float f) {
    unsigned int u = __builtin_bit_cast(unsigned int, f);
    unsigned int r = (u + 0x7fffu + ((u >> 16) & 1u)) >> 16;  // RNE
    return (unsigned short)r;
}

__device__ inline float sigmoidf_(float x) { return 1.0f / (1.0f + __expf(-x)); }

__device__ inline float fast_tanh(float x) {
    x = fminf(fmaxf(x, -15.f), 15.f);
    float e = __expf(2.f * x);
    return (e - 1.f) / (e + 1.f);
}

// ---------------- prep kernels ----------------

__global__ void prep_weights(const float* __restrict__ Wih, const float* __restrict__ Whh,
                             const float* __restrict__ bih, const float* __restrict__ bhh,
                             unsigned short* __restrict__ Wc, unsigned short* __restrict__ Wcat,
                             float* __restrict__ bc) {
    int idx = blockIdx.x * 256 + threadIdx.x;      // < 2048*512
    int n = idx >> 9, k = idx & 511;
    float wi = Wih[idx], wh = Whh[idx];
    Wc[idx] = to_bf16(wi + wh);
    Wcat[(n << 10) + k]       = to_bf16(wi);
    Wcat[(n << 10) + 512 + k] = to_bf16(wh);
    if (k == 0) bc[n] = bih[n] + bhh[n];
}

__global__ void prep_w1(const float* __restrict__ W1, unsigned short* __restrict__ W1b) {
    int idx = blockIdx.x * 256 + threadIdx.x;      // < 512*512
    W1b[idx] = to_bf16(W1[idx]);
}

__global__ void prep_w2(const float* __restrict__ W2, unsigned short* __restrict__ W2b) {
    int idx = blockIdx.x * 256 + threadIdx.x;      // < 16*512
    int o = idx >> 9, k = idx & 511;
    W2b[idx] = (o < OUT_) ? to_bf16(W2[o * H_ + k]) : (unsigned short)0;
}

__global__ void prep_x(const float* __restrict__ x, const float* __restrict__ hx0,
                       unsigned short* __restrict__ xcat) {
    int idx = blockIdx.x * 256 + threadIdx.x;      // < 256*512
    int b = idx >> 9, k = idx & 511;
    xcat[(b << 10) + k]       = to_bf16(x[idx]);
    xcat[(b << 10) + 512 + k] = to_bf16(hx0[idx]);
}

// ---------------- step 0 (K=1024, [x|hx0] @ [Wih|Whh]) ----------------
template <int KLEN>
__global__ __launch_bounds__(256) void lstm_step(
    const unsigned short* __restrict__ A,
    const unsigned short* __restrict__ W,
    const float* __restrict__ bc,
    const float* __restrict__ c_in,
    float* __restrict__ c_out,
    unsigned short* __restrict__ h_out) {
    const int lane = threadIdx.x & 63;
    const int wave = threadIdx.x >> 6;
    const int mn = lane & 15, q = lane >> 4;
    const int rt = blockIdx.x & 15;
    const int hb = (blockIdx.x >> 4) * 64 + wave * 16;

    const unsigned short* ap  = A + (size_t)(rt * 16 + mn) * KLEN + q * 8;
    const unsigned short* wp0 = W + (size_t)(0 * H_ + hb + mn) * KLEN + q * 8;
    const unsigned short* wp1 = W + (size_t)(1 * H_ + hb + mn) * KLEN + q * 8;
    const unsigned short* wp2 = W + (size_t)(2 * H_ + hb + mn) * KLEN + q * 8;
    const unsigned short* wp3 = W + (size_t)(3 * H_ + hb + mn) * KLEN + q * 8;

    f32x4 acc0 = {0.f,0.f,0.f,0.f}, acc1 = {0.f,0.f,0.f,0.f};
    f32x4 acc2 = {0.f,0.f,0.f,0.f}, acc3 = {0.f,0.f,0.f,0.f};
#pragma unroll 4
    for (int k0 = 0; k0 < KLEN; k0 += 32) {
        s16x8 a  = *reinterpret_cast<const s16x8*>(ap + k0);
        s16x8 w0 = *reinterpret_cast<const s16x8*>(wp0 + k0);
        s16x8 w1 = *reinterpret_cast<const s16x8*>(wp1 + k0);
        s16x8 w2 = *reinterpret_cast<const s16x8*>(wp2 + k0);
        s16x8 w3 = *reinterpret_cast<const s16x8*>(wp3 + k0);
        acc0 = __builtin_amdgcn_mfma_f32_16x16x32_bf16(a, w0, acc0, 0, 0, 0);
        acc1 = __builtin_amdgcn_mfma_f32_16x16x32_bf16(a, w1, acc1, 0, 0, 0);
        acc2 = __builtin_amdgcn_mfma_f32_16x16x32_bf16(a, w2, acc2, 0, 0, 0);
        acc3 = __builtin_amdgcn_mfma_f32_16x16x32_bf16(a, w3, acc3, 0, 0, 0);
    }

    const int j = hb + mn;
    const float bi = bc[j], bfv = bc[H_ + j], bg = bc[2 * H_ + j], bo = bc[3 * H_ + j];
#pragma unroll
    for (int r = 0; r < 4; ++r) {
        const int row = rt * 16 + q * 4 + r;
        const float iv = sigmoidf_(acc0[r] + bi);
        const float fv = sigmoidf_(acc1[r] + bfv);
        const float gv = fast_tanh(acc2[r] + bg);
        const float ov = sigmoidf_(acc3[r] + bo);
        const float co = c_in[row * H_ + j];
        const float cn = fv * co + iv * gv;
        c_out[row * H_ + j] = cn;
        h_out[row * H_ + j] = to_bf16(ov * fast_tanh(cn));
    }
}

// ---------------- persistent LSTM + in-barrier MLP (steps 1..325) ----------------
// LSTM core verbatim-R3 (verified): 16 groups (g=blockIdx&15) x 16 WGs,
// 32 cols/WG, counter barrier, swizzled A_lds. MLP overlap on waves 2,3 under
// the straggler spin (as R7), with TWO defensive changes vs R7:
//  (1) launched as a NORMAL kernel (grid 256 = #CUs, >=1 block/CU capacity ->
//      all WGs co-resident; no hipLaunchCooperativeKernel, whose silent
//      launch-failure is the unified explanation of R4/R5/R7's signatures);
//  (2) fp atomicAdd targets ws_y (workspace, definitely device memory; zeroed
//      host-side), and a trivial copy kernel writes out = ws_y with plain
//      stores (the R0-R3-verified path to d_out).
__global__ __launch_bounds__(256) void lstm_persist(
    const unsigned short* __restrict__ Wc,   // [2048][512] bf16
    const float* __restrict__ bc,            // [2048]
    const float* __restrict__ c0,            // [256][512] f32 (from step 0)
    unsigned short* __restrict__ h_hist,     // [326][256][512] bf16
    unsigned int* __restrict__ ctr,          // 16 counters, 128B apart
    const unsigned short* __restrict__ W1b,  // [512][512] bf16
    const float* __restrict__ b1,            // [512]
    const unsigned short* __restrict__ W2b,  // [16][512] bf16 (rows 9..15 zero)
    const float* __restrict__ b2,            // [9]
    float* __restrict__ ws_y) {              // [256][326][9] f32 (zeroed)
    __shared__ unsigned short A_lds[16 * 512];   // 16 KB, swizzled
    __shared__ float gate_lds[4 * 16 * 33];      // 8448 B
    __shared__ unsigned short z_lds[2 * 16 * 24]; // 1536 B (waves 2,3 transpose)
    const int tid = threadIdx.x;
    const int lane = tid & 63, wave = tid >> 6;
    const int mn = lane & 15, q = lane >> 4;
    const int g  = blockIdx.x & 15;              // group (same XCD: g%8)
    const int wg = blockIdx.x >> 4;              // 0..15 within group
    const int jb = wg * 32;                      // 32 cols per WG
    unsigned int* ctr_g = ctr + g * 32;          // own cacheline per group

    // ---- LSTM weights -> registers (verbatim R3) ----
    s16x8 breg[2][16];
#pragma unroll
    for (int n = 0; n < 2; ++n) {
        const unsigned short* wp = Wc + (size_t)(wave * H_ + jb + n * 16 + mn) * H_ + q * 8;
#pragma unroll
        for (int kk = 0; kk < 16; ++kk)
            breg[n][kk] = *reinterpret_cast<const s16x8*>(wp + kk * 32);
    }
    const float bcv0 = bc[wave * H_ + jb + mn];
    const float bcv1 = bc[wave * H_ + jb + 16 + mn];

    // owned c/h: row crow (0..15), adjacent cols cc0..cc0+1 (verbatim R3)
    const int crow = tid >> 4, cc0 = (tid & 15) * 2;
    float c_x = c0[(size_t)(g * 16 + crow) * H_ + jb + cc0];
    float c_y = c0[(size_t)(g * 16 + crow) * H_ + jb + cc0 + 1];

    // swizzled ushort indices (verbatim R3)
    int a_st[8];
#pragma unroll
    for (int p = 0; p < 8; ++p) {
        const int qi = p * 256 + tid;
        const int row = qi >> 7;                 // 128 qwords per 512-col row
        const int bcol = (qi & 127) * 8;
        a_st[p] = row * 512 + ((bcol ^ ((row & 7) << 4)) >> 1);
    }
    int a_rd[16];
#pragma unroll
    for (int kk = 0; kk < 16; ++kk) {
        const int bcol = kk * 64 + q * 16;
        a_rd[kk] = mn * 512 + ((bcol ^ ((mn & 7) << 4)) >> 1);
    }

    // ---- MLP state (waves 2,3 only) ----
    s16x8 w1reg[16];
    s16x8 w2reg = {0,0,0,0,0,0,0,0};
    float b1v = 0.f, b2v = 0.f;
    const int zw = wave - 2;                     // 0,1 for waves 2,3
    if (wave >= 2) {
        const int zbase = wg * 32 + zw * 16;     // this wave's 16 z-cols
        const unsigned short* wp = W1b + (size_t)(zbase + mn) * H_ + q * 8;
#pragma unroll
        for (int kk = 0; kk < 16; ++kk)
            w1reg[kk] = *reinterpret_cast<const s16x8*>(wp + kk * 32);
        b1v = b1[zbase + mn];
        if (q < 2)
            w2reg = *reinterpret_cast<const s16x8*>(W2b + (size_t)mn * H_ + zbase + q * 8);
        b2v = (mn < OUT_ && wg == 0 && wave == 2) ? b2[mn] : 0.f;
    }

    // MLP pass for output index tout, using A_lds (= h_tout). Waves 2,3 only.
    auto mlp_pass = [&](int tout) {
        f32x4 zacc = {0.f,0.f,0.f,0.f};
#pragma unroll
        for (int kk = 0; kk < 16; ++kk) {
            s16x8 a = *reinterpret_cast<const s16x8*>(&A_lds[a_rd[kk]]);
            zacc = __builtin_amdgcn_mfma_f32_16x16x32_bf16(a, w1reg[kk], zacc, 0, 0, 0);
        }
        // z (relu, bf16) -> per-wave LDS [row 16][stride 24]; same-wave transpose
#pragma unroll
        for (int r = 0; r < 4; ++r) {
            float v = zacc[r] + b1v;
            v = v > 0.f ? v : 0.f;
            z_lds[zw * 384 + (q * 4 + r) * 24 + mn] = to_bf16(v);
        }
        s16x8 az = {0,0,0,0,0,0,0,0};
        if (q < 2) az = *reinterpret_cast<const s16x8*>(&z_lds[zw * 384 + mn * 24 + q * 8]);
        f32x4 y = __builtin_amdgcn_mfma_f32_16x16x32_bf16(az, w2reg, f32x4{0.f,0.f,0.f,0.f}, 0, 0, 0);
        if (mn < OUT_) {
#pragma unroll
            for (int r = 0; r < 4; ++r)
                atomicAdd(&ws_y[(size_t)(g * 16 + q * 4 + r) * (T_ * OUT_) + tout * OUT_ + mn],
                          y[r] + b2v);
        }
    };

    for (int t = 1; t < T_; ++t) {
        // ---- stage A = h_{t-1} rows [g*16, g*16+16) via sc1 8B loads ----
        const ull* hsrc64 = reinterpret_cast<const ull*>(
            h_hist + (size_t)(t - 1) * (B_ * H_) + (size_t)g * 16 * H_);
        ull vv[8];
#pragma unroll
        for (int p = 0; p < 8; ++p)
            vv[p] = __hip_atomic_load(hsrc64 + p * 256 + tid, __ATOMIC_RELAXED,
                                      __HIP_MEMORY_SCOPE_AGENT);
#pragma unroll
        for (int p = 0; p < 8; ++p)
            *reinterpret_cast<ull*>(&A_lds[a_st[p]]) = vv[p];
        __syncthreads();

        // ---- gates via MFMA (M=16, N=2x16, K=512) (verbatim R3) ----
        f32x4 acc0 = {0.f,0.f,0.f,0.f}, acc1 = {0.f,0.f,0.f,0.f};
#pragma unroll
        for (int kk = 0; kk < 16; ++kk) {
            s16x8 a = *reinterpret_cast<const s16x8*>(&A_lds[a_rd[kk]]);
            acc0 = __builtin_amdgcn_mfma_f32_16x16x32_bf16(a, breg[0][kk], acc0, 0, 0, 0);
            acc1 = __builtin_amdgcn_mfma_f32_16x16x32_bf16(a, breg[1][kk], acc1, 0, 0, 0);
        }

        // ---- activations -> gate LDS (verbatim R3) ----
#pragma unroll
        for (int r = 0; r < 4; ++r) {
            float v0 = acc0[r] + bcv0, v1 = acc1[r] + bcv1;
            if (wave == 2) { v0 = fast_tanh(v0); v1 = fast_tanh(v1); }
            else           { v0 = sigmoidf_(v0); v1 = sigmoidf_(v1); }
            gate_lds[(wave * 16 + (q * 4 + r)) * 33 + mn]      = v0;
            gate_lds[(wave * 16 + (q * 4 + r)) * 33 + 16 + mn] = v1;
        }
        __syncthreads();

        // ---- c/h update (verbatim R3) ----
        {
            float iv0 = gate_lds[(0 * 16 + crow) * 33 + cc0], iv1 = gate_lds[(0 * 16 + crow) * 33 + cc0 + 1];
            float fv0 = gate_lds[(1 * 16 + crow) * 33 + cc0], fv1 = gate_lds[(1 * 16 + crow) * 33 + cc0 + 1];
            float gv0 = gate_lds[(2 * 16 + crow) * 33 + cc0], gv1 = gate_lds[(2 * 16 + crow) * 33 + cc0 + 1];
            float ov0 = gate_lds[(3 * 16 + crow) * 33 + cc0], ov1 = gate_lds[(3 * 16 + crow) * 33 + cc0 + 1];
            c_x = fv0 * c_x + iv0 * gv0;
            c_y = fv1 * c_y + iv1 * gv1;
            unsigned int h0 = to_bf16(ov0 * fast_tanh(c_x));
            unsigned int h1 = to_bf16(ov1 * fast_tanh(c_y));
            unsigned int packed = h0 | (h1 << 16);
            unsigned int* hdst = reinterpret_cast<unsigned int*>(
                h_hist + (size_t)t * (B_ * H_) + (size_t)(g * 16 + crow) * H_ + jb + cc0);
            __hip_atomic_store(hdst, packed, __ATOMIC_RELAXED, __HIP_MEMORY_SCOPE_AGENT);
        }

        // ---- per-group barrier (R3 mechanics, EVERY step) ----
        // MLP for output t-1 runs on waves 2,3 under tid0's straggler spin.
        __syncthreads();  // emits s_waitcnt vmcnt(0): sc1 h-stores complete
        asm volatile("" ::: "memory");
        if (tid == 0) {
            __hip_atomic_fetch_add(ctr_g, 1u, __ATOMIC_RELAXED, __HIP_MEMORY_SCOPE_AGENT);
            const unsigned int target = 16u * (unsigned int)t;
            while (__hip_atomic_load(ctr_g, __ATOMIC_RELAXED, __HIP_MEMORY_SCOPE_AGENT) < target) {
            }
        }
        if (wave >= 2) mlp_pass(t - 1);
        asm volatile("" ::: "memory");
        __syncthreads();
    }

    // ---- epilogue: output 325 from h_325 (own group all published) ----
    {
        const ull* hsrc64 = reinterpret_cast<const ull*>(
            h_hist + (size_t)(T_ - 1) * (B_ * H_) + (size_t)g * 16 * H_);
        ull vv[8];
#pragma unroll
        for (int p = 0; p < 8; ++p)
            vv[p] = __hip_atomic_load(hsrc64 + p * 256 + tid, __ATOMIC_RELAXED,
                                      __HIP_MEMORY_SCOPE_AGENT);
#pragma unroll
        for (int p = 0; p < 8; ++p)
            *reinterpret_cast<ull*>(&A_lds[a_st[p]]) = vv[p];
        __syncthreads();
        if (wave >= 2) mlp_pass(T_ - 1);
    }
}

// ---------------- copy ws_y -> out (plain stores to d_out) ----------------
__global__ void copy_out(const float* __restrict__ ws_y, float* __restrict__ out) {
    int idx = blockIdx.x * 256 + threadIdx.x;    // < 256*326*9 = 751104
    out[idx] = ws_y[idx];
}

// ---------------- host launch ----------------
extern "C" void kernel_launch(void* const* d_in, const int* in_sizes, int n_in,
                              void* d_out, int out_size, void* d_ws, size_t ws_size,
                              hipStream_t stream) {
    (void)in_sizes; (void)n_in; (void)out_size;
    const float* x   = (const float*)d_in[0];
    const float* hx0 = (const float*)d_in[1];
    const float* cx0 = (const float*)d_in[2];
    const float* Wih = (const float*)d_in[3];
    const float* Whh = (const float*)d_in[4];
    const float* bih = (const float*)d_in[5];
    const float* bhh = (const float*)d_in[6];
    const float* W1  = (const float*)d_in[7];
    const float* b1  = (const float*)d_in[8];
    const float* W2  = (const float*)d_in[9];
    const float* b2  = (const float*)d_in[10];
    float* out = (float*)d_out;

    char* p = (char*)d_ws;
    size_t off = 0;
    auto alloc = [&](size_t bytes) {
        void* r = p + off;
        off = (off + bytes + 255) & ~(size_t)255;
        return r;
    };
    unsigned short* Wc     = (unsigned short*)alloc((size_t)G4_ * H_ * 2);
    unsigned short* Wcat   = (unsigned short*)alloc((size_t)G4_ * 1024 * 2);
    unsigned short* W1b    = (unsigned short*)alloc((size_t)H_ * H_ * 2);
    unsigned short* W2b    = (unsigned short*)alloc((size_t)16 * H_ * 2);
    float*          bc     = (float*)alloc((size_t)G4_ * 4);
    unsigned short* xcat   = (unsigned short*)alloc((size_t)B_ * 1024 * 2);
    float*          cbuf   = (float*)alloc((size_t)B_ * H_ * 4);
    unsigned int*   ctr    = (unsigned int*)alloc(4096);
    float*          ws_y   = (float*)alloc((size_t)B_ * T_ * OUT_ * 4);
    unsigned short* h_hist = (unsigned short*)alloc((size_t)T_ * B_ * H_ * 2);
    if (off > ws_size) {
        fprintf(stderr, "kernel_launch: ws too small: need %zu have %zu\n", off, ws_size);
        return;
    }

    prep_weights<<<G4_ * H_ / 256, 256, 0, stream>>>(Wih, Whh, bih, bhh, Wc, Wcat, bc);
    prep_w1<<<H_ * H_ / 256, 256, 0, stream>>>(W1, W1b);
    prep_w2<<<16 * H_ / 256, 256, 0, stream>>>(W2, W2b);
    prep_x<<<B_ * H_ / 256, 256, 0, stream>>>(x, hx0, xcat);

    // step 0: K=1024
    lstm_step<1024><<<128, 256, 0, stream>>>(xcat, Wcat, bc, cx0, cbuf, h_hist);

    // zero group counters + y accumulator, then persistent steps 1..325
    hipMemsetAsync(ctr, 0, 4096, stream);
    hipMemsetAsync(ws_y, 0, (size_t)B_ * T_ * OUT_ * 4, stream);

    // NORMAL launch (not cooperative): grid 256 = #CUs, 26KB LDS, VGPR<=512
    // -> >=1 block/CU capacity -> all WGs co-resident; spin barriers safe.
    lstm_persist<<<256, 256, 0, stream>>>(Wc, bc, cbuf, h_hist, ctr,
                                          W1b, b1, W2b, b2, ws_y);

    copy_out<<<(B_ * T_ * OUT_) / 256, 256, 0, stream>>>(ws_y, out);
}